// Round 19
// baseline (53.795 us; speedup 1.0000x reference)
//
#include <hip/hip_runtime.h>
#include <hip/hip_bf16.h>

// GraphAttentionLayer: N=16, Cin=64, T=512, V=64. Per b = n*T+t.
// r13 base (53.1us best) + mm2 switched to r3's own-P-rows form, allowing
// DELETION of barrier 3: softmax wave w writes P rows 16w..16w+15; mm2 wave w
// reads ONLY those P rows (in-order per-wave DS pipe orders it, r5/r9-proven);
// Y reads (cross-wave) remain covered by barrier 2. Barriers: 3 -> 2.
// Phases: stage(X,Wt) -> bar -> mm1 (+f/g partials) -> bar ->
//         softmax rows 16w..16w+15 -> [no barrier] -> mm2 (own P, all Y rows).

using bf16x8 = __attribute__((ext_vector_type(8))) short;
using f32x4  = __attribute__((ext_vector_type(4))) float;
typedef unsigned long long ull;

constexpr float ALPHA = 0.2f;

__device__ __forceinline__ unsigned short f2bf(float f) {
    union { __hip_bfloat16 h; unsigned short s; } u;
    u.h = __float2bfloat16(f);
    return u.s;
}

// prep (1 block, 256 thr): Wt[v][u]=bf16(W[u][v]);
// maskT[j] bit i = (Asum[i][j]>0); rowzero bit i = (row i all <=0)
__global__ void prep_kernel(const float* __restrict__ A,
                            const float* __restrict__ W,
                            unsigned short* __restrict__ Wt,
                            ull* __restrict__ maskT,
                            ull* __restrict__ rowzero) {
    __shared__ unsigned short part[64][4];
    __shared__ ull rowm[64];
    const int tid = threadIdx.x;
    {
        const int v = tid & 63, q = tid >> 6;
        #pragma unroll 4
        for (int m = 0; m < 16; ++m) {
            const int u = 16 * q + m;
            Wt[v * 64 + u] = f2bf(W[u * 64 + v]);
        }
    }
    {
        const int i = tid >> 2, q = tid & 3;
        const float4* a0 = (const float4*)(A + i * 64 + q * 16);
        const float4* a1 = (const float4*)(A + 4096 + i * 64 + q * 16);
        const float4* a2 = (const float4*)(A + 8192 + i * 64 + q * 16);
        unsigned m16 = 0;
        #pragma unroll
        for (int j4 = 0; j4 < 4; ++j4) {
            float4 s0 = a0[j4], s1 = a1[j4], s2 = a2[j4];
            if (s0.x + s1.x + s2.x > 0.f) m16 |= 1u << (4 * j4 + 0);
            if (s0.y + s1.y + s2.y > 0.f) m16 |= 1u << (4 * j4 + 1);
            if (s0.z + s1.z + s2.z > 0.f) m16 |= 1u << (4 * j4 + 2);
            if (s0.w + s1.w + s2.w > 0.f) m16 |= 1u << (4 * j4 + 3);
        }
        part[i][q] = (unsigned short)m16;
    }
    __syncthreads();
    if (tid < 64) {
        ull m = (ull)part[tid][0] | ((ull)part[tid][1] << 16)
              | ((ull)part[tid][2] << 32) | ((ull)part[tid][3] << 48);
        rowm[tid] = m;
        ull bz = __ballot(m == 0ull);
        if (tid == 0) rowzero[0] = bz;
    }
    __syncthreads();
    if (tid < 64) {
        ull mt = 0;
        for (int i = 0; i < 64; ++i) mt |= ((rowm[i] >> tid) & 1ull) << i;
        maskT[tid] = mt;
    }
}

__global__ __launch_bounds__(256, 6) void gat_kernel(
    const float* __restrict__ x,                    // (16,64,512,64)
    const float* __restrict__ a,                    // (128,)
    const unsigned short* __restrict__ Wt,          // (64,64) bf16 [v][u]
    const ull* __restrict__ maskT,                  // (64,)
    const ull* __restrict__ rowzero_p,              // (1,)
    float* __restrict__ out)                        // (16,64,512,64)
{
    // stride-72 ushort rows: b128 row-parallel access <=2-way on banks (free)
    // LDS = 9216 + 9216 + 1024 + 1024 = 20480 B.
    __shared__ unsigned short XbYb[64 * 72];  // X (mm1 A) then Yb (mm2 B)
    __shared__ unsigned short WtPb[64 * 72];  // Wt (mm1 B^T) then P (mm2 own rows)
    __shared__ float fpart[4][64];
    __shared__ float gpart[4][64];

    const int tid  = threadIdx.x;
    const int b    = blockIdx.x;
    const int n    = b >> 9, t = b & 511;
    const int w    = tid >> 6, lane = tid & 63;
    const int fr   = lane & 15;
    const int hi   = lane >> 4;
    const int fk   = hi * 8;

    // per-lane transposed mask (VGPR) + uniform empty-row bitmap (SGPR)
    const ull mT = maskT[lane];
    const ull rz = rowzero_p[0];
    // a vectors from global (512B, L2-hot)
    const float4 a1v = *(const float4*)&a[16 * w + 4 * hi];
    const float4 a2v = *(const float4*)&a[64 + 16 * w + 4 * hi];

    // ---- stage X (fp32 -> bf16), coalesced float4, b128 LDS writes ----
    {
        const int c = tid >> 2, q = tid & 3;
        const float* xp = x + (size_t)n * 2097152 + (size_t)c * 32768 + (size_t)t * 64 + q * 16;
        float4 v0 = ((const float4*)xp)[0];
        float4 v1 = ((const float4*)xp)[1];
        float4 v2 = ((const float4*)xp)[2];
        float4 v3 = ((const float4*)xp)[3];
        union { bf16x8 v; unsigned short s[8]; } u0, u1;
        u0.s[0]=f2bf(v0.x); u0.s[1]=f2bf(v0.y); u0.s[2]=f2bf(v0.z); u0.s[3]=f2bf(v0.w);
        u0.s[4]=f2bf(v1.x); u0.s[5]=f2bf(v1.y); u0.s[6]=f2bf(v1.z); u0.s[7]=f2bf(v1.w);
        u1.s[0]=f2bf(v2.x); u1.s[1]=f2bf(v2.y); u1.s[2]=f2bf(v2.z); u1.s[3]=f2bf(v2.w);
        u1.s[4]=f2bf(v3.x); u1.s[5]=f2bf(v3.y); u1.s[6]=f2bf(v3.z); u1.s[7]=f2bf(v3.w);
        *(bf16x8*)&XbYb[c * 72 + q * 16]     = u0.v;
        *(bf16x8*)&XbYb[c * 72 + q * 16 + 8] = u1.v;
    }
    // ---- stage Wt (prepped bf16): 2 coalesced b128 copies per thread ----
    #pragma unroll
    for (int p = 0; p < 2; ++p) {
        const int r  = (tid >> 3) + 32 * p;
        const int cc = (tid & 7) * 8;
        *(bf16x8*)&WtPb[r * 72 + cc] = *(const bf16x8*)&Wt[r * 64 + cc];
    }
    __syncthreads();

    // ---- mm1: Y = X @ W (B from LDS); epilogue: Yb + f/g partials ----
    {
        f32x4 acc[4] = {{0,0,0,0},{0,0,0,0},{0,0,0,0},{0,0,0,0}};
        #pragma unroll
        for (int kc = 0; kc < 2; ++kc) {
            bf16x8 af = *(const bf16x8*)&XbYb[(16 * w + fr) * 72 + 32 * kc + fk];
            #pragma unroll
            for (int cb = 0; cb < 4; ++cb) {
                bf16x8 bfr = *(const bf16x8*)&WtPb[(16 * cb + fr) * 72 + 32 * kc + fk];
                acc[cb] = __builtin_amdgcn_mfma_f32_16x16x32_bf16(af, bfr, acc[cb], 0, 0, 0);
            }
        }
        #pragma unroll
        for (int cb = 0; cb < 4; ++cb) {
            #pragma unroll
            for (int r = 0; r < 4; ++r)
                XbYb[(16 * w + 4 * hi + r) * 72 + 16 * cb + fr] = f2bf(acc[cb][r]);
            float F = acc[cb][0]*a1v.x + acc[cb][1]*a1v.y + acc[cb][2]*a1v.z + acc[cb][3]*a1v.w;
            float G = acc[cb][0]*a2v.x + acc[cb][1]*a2v.y + acc[cb][2]*a2v.z + acc[cb][3]*a2v.w;
            F += __shfl_xor(F, 16, 64); F += __shfl_xor(F, 32, 64);
            G += __shfl_xor(G, 16, 64); G += __shfl_xor(G, 32, 64);
            if (lane < 16) {
                fpart[w][16 * cb + lane] = F;
                gpart[w][16 * cb + lane] = G;
            }
        }
    }
    __syncthreads();   // publishes Yb + fpart/gpart (covers mm2's Y reads too)

    // ---- softmax rows 16w..16w+15 (unnormalized); fi via readlane ----
    {
        const float gj = (gpart[0][lane] + gpart[1][lane]) + (gpart[2][lane] + gpart[3][lane]);
        const int myv = 16 * w + fr;
        const float ftot = (fpart[0][myv] + fpart[1][myv]) + (fpart[2][myv] + fpart[3][myv]);
        #pragma unroll
        for (int k = 0; k < 16; ++k) {
            const int i = 16 * w + k;
            const float fi = __int_as_float(
                __builtin_amdgcn_readlane(__float_as_int(ftot), k));
            const float s0 = fi + gj;
            const float e  = fmaxf(s0, ALPHA * s0);
            const bool keep = (mT >> i) & 1ull;
            const bool zrow = (rz >> i) & 1ull;
            const float p = zrow ? 1.0f : (keep ? __expf(e) : 0.0f);
            WtPb[i * 72 + lane] = f2bf(p);
        }
    }
    // NO barrier: mm2 reads only P rows 16w+fr — own-wave writes, DS in-order.

    // ---- mm2 (own-P-rows form): out[c, v=16w+fr] = sum_j Yb[c,j]P[v,j] / S_v ----
    {
        union { bf16x8 v; unsigned short s[8]; } ones;
        #pragma unroll
        for (int j = 0; j < 8; ++j) ones.s[j] = 0x3f80;   // bf16 1.0
        bf16x8 pb0 = *(const bf16x8*)&WtPb[(16 * w + fr) * 72 + fk];
        bf16x8 pb1 = *(const bf16x8*)&WtPb[(16 * w + fr) * 72 + 32 + fk];
        f32x4 accS = {0, 0, 0, 0};
        accS = __builtin_amdgcn_mfma_f32_16x16x32_bf16(ones.v, pb0, accS, 0, 0, 0);
        accS = __builtin_amdgcn_mfma_f32_16x16x32_bf16(ones.v, pb1, accS, 0, 0, 0);
        f32x4 acc2[4] = {{0,0,0,0},{0,0,0,0},{0,0,0,0},{0,0,0,0}};
        #pragma unroll
        for (int rb = 0; rb < 4; ++rb) {
            bf16x8 y0 = *(const bf16x8*)&XbYb[(16 * rb + fr) * 72 + fk];
            bf16x8 y1 = *(const bf16x8*)&XbYb[(16 * rb + fr) * 72 + 32 + fk];
            acc2[rb] = __builtin_amdgcn_mfma_f32_16x16x32_bf16(y0, pb0, acc2[rb], 0, 0, 0);
            acc2[rb] = __builtin_amdgcn_mfma_f32_16x16x32_bf16(y1, pb1, acc2[rb], 0, 0, 0);
        }
        const float rs = __builtin_amdgcn_rcpf(accS[0]);   // S_v, v = 16w+fr
        float* op = out + (size_t)n * 2097152 + (size_t)t * 64 + 16 * w + fr;
        #pragma unroll
        for (int rb = 0; rb < 4; ++rb)
            #pragma unroll
            for (int r = 0; r < 4; ++r)
                op[(size_t)(16 * rb + 4 * hi + r) * 32768] = acc2[rb][r] * rs;
    }
}

extern "C" void kernel_launch(void* const* d_in, const int* in_sizes, int n_in,
                              void* d_out, int out_size, void* d_ws, size_t ws_size,
                              hipStream_t stream) {
    const float* x = (const float*)d_in[0];
    const float* A = (const float*)d_in[1];
    const float* W = (const float*)d_in[2];
    const float* a = (const float*)d_in[3];
    float* out = (float*)d_out;
    unsigned short* Wt = (unsigned short*)d_ws;          // 8192 B
    ull* maskT   = (ull*)((char*)d_ws + 8192);           // 512 B
    ull* rowzero = (ull*)((char*)d_ws + 8704);           // 8 B

    prep_kernel<<<1, 256, 0, stream>>>(A, W, Wt, maskT, rowzero);
    gat_kernel<<<16 * 512, 256, 0, stream>>>(x, a, Wt, maskT, rowzero, out);
}

// Round 20
// 53.682 us; speedup vs baseline: 1.0021x; 1.0021x over previous
//
#include <hip/hip_runtime.h>
#include <hip/hip_bf16.h>

// GraphAttentionLayer: N=16, Cin=64, T=512, V=64.
// PAIRED-b blocks: 512 threads, waves 0-3 -> b=2bb, waves 4-7 -> b=2bb+1,
// CONCURRENT (per-b code identical to r13/53.1us, double-buffered by half).
// LDS = 2x20480 = 40960 B; 4 blocks/CU x 40960 = 160KiB exactly -> 32
// waves/CU forced. Barrier instances halve (each covers 2 b's).
// Phases per b: stage(X,Wt) -> bar -> mm1 (+f/g partials) -> bar ->
//               softmax rows 16w..16w+15 -> bar -> mm2 (ones-MFMA rowsum).

using bf16x8 = __attribute__((ext_vector_type(8))) short;
using f32x4  = __attribute__((ext_vector_type(4))) float;
typedef unsigned long long ull;

constexpr float ALPHA = 0.2f;

__device__ __forceinline__ unsigned short f2bf(float f) {
    union { __hip_bfloat16 h; unsigned short s; } u;
    u.h = __float2bfloat16(f);
    return u.s;
}

// prep (1 block, 256 thr): Wt[v][u]=bf16(W[u][v]);
// maskT[j] bit i = (Asum[i][j]>0); rowzero bit i = (row i all <=0)
__global__ void prep_kernel(const float* __restrict__ A,
                            const float* __restrict__ W,
                            unsigned short* __restrict__ Wt,
                            ull* __restrict__ maskT,
                            ull* __restrict__ rowzero) {
    __shared__ unsigned short part[64][4];
    __shared__ ull rowm[64];
    const int tid = threadIdx.x;
    {
        const int v = tid & 63, q = tid >> 6;
        #pragma unroll 4
        for (int m = 0; m < 16; ++m) {
            const int u = 16 * q + m;
            Wt[v * 64 + u] = f2bf(W[u * 64 + v]);
        }
    }
    {
        const int i = tid >> 2, q = tid & 3;
        const float4* a0 = (const float4*)(A + i * 64 + q * 16);
        const float4* a1 = (const float4*)(A + 4096 + i * 64 + q * 16);
        const float4* a2 = (const float4*)(A + 8192 + i * 64 + q * 16);
        unsigned m16 = 0;
        #pragma unroll
        for (int j4 = 0; j4 < 4; ++j4) {
            float4 s0 = a0[j4], s1 = a1[j4], s2 = a2[j4];
            if (s0.x + s1.x + s2.x > 0.f) m16 |= 1u << (4 * j4 + 0);
            if (s0.y + s1.y + s2.y > 0.f) m16 |= 1u << (4 * j4 + 1);
            if (s0.z + s1.z + s2.z > 0.f) m16 |= 1u << (4 * j4 + 2);
            if (s0.w + s1.w + s2.w > 0.f) m16 |= 1u << (4 * j4 + 3);
        }
        part[i][q] = (unsigned short)m16;
    }
    __syncthreads();
    if (tid < 64) {
        ull m = (ull)part[tid][0] | ((ull)part[tid][1] << 16)
              | ((ull)part[tid][2] << 32) | ((ull)part[tid][3] << 48);
        rowm[tid] = m;
        ull bz = __ballot(m == 0ull);
        if (tid == 0) rowzero[0] = bz;
    }
    __syncthreads();
    if (tid < 64) {
        ull mt = 0;
        for (int i = 0; i < 64; ++i) mt |= ((rowm[i] >> tid) & 1ull) << i;
        maskT[tid] = mt;
    }
}

__global__ __launch_bounds__(512, 8) void gat_kernel(
    const float* __restrict__ x,                    // (16,64,512,64)
    const float* __restrict__ a,                    // (128,)
    const unsigned short* __restrict__ Wt,          // (64,64) bf16 [v][u]
    const ull* __restrict__ maskT,                  // (64,)
    const ull* __restrict__ rowzero_p,              // (1,)
    float* __restrict__ out)                        // (16,64,512,64)
{
    // Per-half stride-72 ushort rows (<=2-way banks). LDS total:
    // 2*9216*2 + 2*1024*2 = 40960 B; 4 blocks/CU = 160KiB exactly.
    __shared__ unsigned short XbYb[2][64 * 72];  // X (mm1 A) then Yb (mm2 A)
    __shared__ unsigned short WtPb[2][64 * 72];  // Wt (mm1 B^T) then P (mm2 B^T)
    __shared__ float fpart[2][4][64];
    __shared__ float gpart[2][4][64];

    const int tid  = threadIdx.x;          // 0..511
    const int half = tid >> 8;             // 0..1 -> which b
    const int htid = tid & 255;            // 0..255 within half
    const int b    = (blockIdx.x << 1) | half;
    const int n    = b >> 9, t = b & 511;
    const int w    = htid >> 6, lane = htid & 63;
    const int fr   = lane & 15;
    const int hi   = lane >> 4;
    const int fk   = hi * 8;

    unsigned short* Xb = &XbYb[half][0];
    unsigned short* Pp = &WtPb[half][0];

    // per-lane transposed mask (VGPR) + uniform empty-row bitmap (SGPR)
    const ull mT = maskT[lane];
    const ull rz = rowzero_p[0];
    // a vectors from global (512B, L2-hot)
    const float4 a1v = *(const float4*)&a[16 * w + 4 * hi];
    const float4 a2v = *(const float4*)&a[64 + 16 * w + 4 * hi];

    // ---- stage X (fp32 -> bf16), coalesced float4, b128 LDS writes ----
    {
        const int c = htid >> 2, q = htid & 3;
        const float* xp = x + (size_t)n * 2097152 + (size_t)c * 32768 + (size_t)t * 64 + q * 16;
        float4 v0 = ((const float4*)xp)[0];
        float4 v1 = ((const float4*)xp)[1];
        float4 v2 = ((const float4*)xp)[2];
        float4 v3 = ((const float4*)xp)[3];
        union { bf16x8 v; unsigned short s[8]; } u0, u1;
        u0.s[0]=f2bf(v0.x); u0.s[1]=f2bf(v0.y); u0.s[2]=f2bf(v0.z); u0.s[3]=f2bf(v0.w);
        u0.s[4]=f2bf(v1.x); u0.s[5]=f2bf(v1.y); u0.s[6]=f2bf(v1.z); u0.s[7]=f2bf(v1.w);
        u1.s[0]=f2bf(v2.x); u1.s[1]=f2bf(v2.y); u1.s[2]=f2bf(v2.z); u1.s[3]=f2bf(v2.w);
        u1.s[4]=f2bf(v3.x); u1.s[5]=f2bf(v3.y); u1.s[6]=f2bf(v3.z); u1.s[7]=f2bf(v3.w);
        *(bf16x8*)&Xb[c * 72 + q * 16]     = u0.v;
        *(bf16x8*)&Xb[c * 72 + q * 16 + 8] = u1.v;
    }
    // ---- stage Wt (prepped bf16): 2 coalesced b128 copies per thread ----
    #pragma unroll
    for (int p = 0; p < 2; ++p) {
        const int r  = (htid >> 3) + 32 * p;
        const int cc = (htid & 7) * 8;
        *(bf16x8*)&Pp[r * 72 + cc] = *(const bf16x8*)&Wt[r * 64 + cc];
    }
    __syncthreads();

    // ---- mm1: Y = X @ W (B from LDS); epilogue: Yb + f/g partials ----
    {
        f32x4 acc[4] = {{0,0,0,0},{0,0,0,0},{0,0,0,0},{0,0,0,0}};
        #pragma unroll
        for (int kc = 0; kc < 2; ++kc) {
            bf16x8 af = *(const bf16x8*)&Xb[(16 * w + fr) * 72 + 32 * kc + fk];
            #pragma unroll
            for (int cb = 0; cb < 4; ++cb) {
                bf16x8 bfr = *(const bf16x8*)&Pp[(16 * cb + fr) * 72 + 32 * kc + fk];
                acc[cb] = __builtin_amdgcn_mfma_f32_16x16x32_bf16(af, bfr, acc[cb], 0, 0, 0);
            }
        }
        #pragma unroll
        for (int cb = 0; cb < 4; ++cb) {
            #pragma unroll
            for (int r = 0; r < 4; ++r)
                Xb[(16 * w + 4 * hi + r) * 72 + 16 * cb + fr] = f2bf(acc[cb][r]);
            float F = acc[cb][0]*a1v.x + acc[cb][1]*a1v.y + acc[cb][2]*a1v.z + acc[cb][3]*a1v.w;
            float G = acc[cb][0]*a2v.x + acc[cb][1]*a2v.y + acc[cb][2]*a2v.z + acc[cb][3]*a2v.w;
            F += __shfl_xor(F, 16, 64); F += __shfl_xor(F, 32, 64);
            G += __shfl_xor(G, 16, 64); G += __shfl_xor(G, 32, 64);
            if (lane < 16) {
                fpart[half][w][16 * cb + lane] = F;
                gpart[half][w][16 * cb + lane] = G;
            }
        }
    }
    __syncthreads();

    // ---- softmax rows 16w..16w+15 (unnormalized); fi via readlane ----
    {
        const float gj = (gpart[half][0][lane] + gpart[half][1][lane])
                       + (gpart[half][2][lane] + gpart[half][3][lane]);
        const int myv = 16 * w + fr;
        const float ftot = (fpart[half][0][myv] + fpart[half][1][myv])
                         + (fpart[half][2][myv] + fpart[half][3][myv]);
        #pragma unroll
        for (int k = 0; k < 16; ++k) {
            const int i = 16 * w + k;
            const float fi = __int_as_float(
                __builtin_amdgcn_readlane(__float_as_int(ftot), k));
            const float s0 = fi + gj;
            const float e  = fmaxf(s0, ALPHA * s0);
            const bool keep = (mT >> i) & 1ull;
            const bool zrow = (rz >> i) & 1ull;
            const float p = zrow ? 1.0f : (keep ? __expf(e) : 0.0f);
            Pp[i * 72 + lane] = f2bf(p);
        }
    }
    __syncthreads();

    // ---- mm2: out[c,v] = (sum_j Yb[c,j]*P[v,j]) * rcp(S_v); S via ones-MFMA ----
    {
        f32x4 acc2[4] = {{0,0,0,0},{0,0,0,0},{0,0,0,0},{0,0,0,0}};
        f32x4 accS[4] = {{0,0,0,0},{0,0,0,0},{0,0,0,0},{0,0,0,0}};
        union { bf16x8 v; unsigned short s[8]; } ones;
        #pragma unroll
        for (int j = 0; j < 8; ++j) ones.s[j] = 0x3f80;   // bf16 1.0
        #pragma unroll
        for (int kc = 0; kc < 2; ++kc) {
            bf16x8 af = *(const bf16x8*)&Xb[(16 * w + fr) * 72 + 32 * kc + fk];
            #pragma unroll
            for (int cb = 0; cb < 4; ++cb) {
                bf16x8 bfr = *(const bf16x8*)&Pp[(16 * cb + fr) * 72 + 32 * kc + fk];
                acc2[cb] = __builtin_amdgcn_mfma_f32_16x16x32_bf16(af, bfr, acc2[cb], 0, 0, 0);
                accS[cb] = __builtin_amdgcn_mfma_f32_16x16x32_bf16(ones.v, bfr, accS[cb], 0, 0, 0);
            }
        }
        float* op = out + (size_t)n * 2097152 + (size_t)t * 64;
        #pragma unroll
        for (int cb = 0; cb < 4; ++cb) {
            const float rs  = __builtin_amdgcn_rcpf(accS[cb][0]);
            const int   col = 16 * cb + fr;
            #pragma unroll
            for (int r = 0; r < 4; ++r) {
                const int row = 16 * w + 4 * hi + r;
                op[(size_t)row * 32768 + col] = acc2[cb][r] * rs;
            }
        }
    }
}

extern "C" void kernel_launch(void* const* d_in, const int* in_sizes, int n_in,
                              void* d_out, int out_size, void* d_ws, size_t ws_size,
                              hipStream_t stream) {
    const float* x = (const float*)d_in[0];
    const float* A = (const float*)d_in[1];
    const float* W = (const float*)d_in[2];
    const float* a = (const float*)d_in[3];
    float* out = (float*)d_out;
    unsigned short* Wt = (unsigned short*)d_ws;          // 8192 B
    ull* maskT   = (ull*)((char*)d_ws + 8192);           // 512 B
    ull* rowzero = (ull*)((char*)d_ws + 8704);           // 8 B

    prep_kernel<<<1, 256, 0, stream>>>(A, W, Wt, maskT, rowzero);
    gat_kernel<<<4096, 512, 0, stream>>>(x, a, Wt, maskT, rowzero, out);
}

// Round 21
// 51.943 us; speedup vs baseline: 1.0356x; 1.0335x over previous
//
#include <hip/hip_runtime.h>
#include <hip/hip_bf16.h>

// GraphAttentionLayer: N=16, Cin=64, T=512, V=64. Per b = n*T+t.
// gat kernel = r13 byte-identical (53.1us best). Prep head shrunk:
//   - 2 concurrent blocks: block 1 = Wt convert, block 0 = masks
//   - mask transpose via 64x __ballot (VALU, own-register) instead of the
//     64-iteration LDS-read loop; drops rowm[] array + one barrier.
// Phases (gat): stage(X,Wt) -> bar -> mm1 (+f/g partials) -> bar ->
//         softmax rows 16w..16w+15 (unnormalized) -> bar -> mm2 (ones-MFMA rowsum).

using bf16x8 = __attribute__((ext_vector_type(8))) short;
using f32x4  = __attribute__((ext_vector_type(4))) float;
typedef unsigned long long ull;

constexpr float ALPHA = 0.2f;

__device__ __forceinline__ unsigned short f2bf(float f) {
    union { __hip_bfloat16 h; unsigned short s; } u;
    u.h = __float2bfloat16(f);
    return u.s;
}

// prep, grid=2: block 1 -> Wt[v][u]=bf16(W[u][v]); block 0 -> maskT + rowzero.
__global__ void prep_kernel(const float* __restrict__ A,
                            const float* __restrict__ W,
                            unsigned short* __restrict__ Wt,
                            ull* __restrict__ maskT,
                            ull* __restrict__ rowzero) {
    const int tid = threadIdx.x;
    if (blockIdx.x == 1) {
        // Wt convert: 256 threads, v = tid&63, q = tid>>6 covers u = 16q..16q+15
        const int v = tid & 63, q = tid >> 6;
        #pragma unroll 4
        for (int m = 0; m < 16; ++m) {
            const int u = 16 * q + m;
            Wt[v * 64 + u] = f2bf(W[u * 64 + v]);
        }
        return;
    }
    // mask block: coalesced row sums -> per-row bitmask -> ballot transpose
    __shared__ unsigned short part[64][4];
    {
        const int i = tid >> 2, q = tid & 3;
        const float4* a0 = (const float4*)(A + i * 64 + q * 16);
        const float4* a1 = (const float4*)(A + 4096 + i * 64 + q * 16);
        const float4* a2 = (const float4*)(A + 8192 + i * 64 + q * 16);
        unsigned m16 = 0;
        #pragma unroll
        for (int j4 = 0; j4 < 4; ++j4) {
            float4 s0 = a0[j4], s1 = a1[j4], s2 = a2[j4];
            if (s0.x + s1.x + s2.x > 0.f) m16 |= 1u << (4 * j4 + 0);
            if (s0.y + s1.y + s2.y > 0.f) m16 |= 1u << (4 * j4 + 1);
            if (s0.z + s1.z + s2.z > 0.f) m16 |= 1u << (4 * j4 + 2);
            if (s0.w + s1.w + s2.w > 0.f) m16 |= 1u << (4 * j4 + 3);
        }
        part[i][q] = (unsigned short)m16;
    }
    __syncthreads();
    if (tid < 64) {
        // rowm for my row (own-register), no LDS array needed afterwards
        const ull m = (ull)part[tid][0] | ((ull)part[tid][1] << 16)
                    | ((ull)part[tid][2] << 32) | ((ull)part[tid][3] << 48);
        const ull bz = __ballot(m == 0ull);
        if (tid == 0) rowzero[0] = bz;
        // transpose via ballot: iteration j computes maskT[j] (bit i = rowm[i] bit j)
        ull mt = 0;
        #pragma unroll 8
        for (int j = 0; j < 64; ++j) {
            const ull bt = __ballot((m >> j) & 1ull);
            if (tid == j) mt = bt;
        }
        maskT[tid] = mt;
    }
}

__global__ __launch_bounds__(256, 6) void gat_kernel(
    const float* __restrict__ x,                    // (16,64,512,64)
    const float* __restrict__ a,                    // (128,)
    const unsigned short* __restrict__ Wt,          // (64,64) bf16 [v][u]
    const ull* __restrict__ maskT,                  // (64,)
    const ull* __restrict__ rowzero_p,              // (1,)
    float* __restrict__ out)                        // (16,64,512,64)
{
    // stride-72 ushort rows: b128 row-parallel access <=2-way on banks (free)
    // LDS = 9216 + 9216 + 1024 + 1024 = 20480 B.
    __shared__ unsigned short XbYb[64 * 72];  // X (mm1 A) then Yb (mm2 A)
    __shared__ unsigned short WtPb[64 * 72];  // Wt (mm1 B^T) then P (mm2 B^T)
    __shared__ float fpart[4][64];
    __shared__ float gpart[4][64];

    const int tid  = threadIdx.x;
    const int b    = blockIdx.x;
    const int n    = b >> 9, t = b & 511;
    const int w    = tid >> 6, lane = tid & 63;
    const int fr   = lane & 15;
    const int hi   = lane >> 4;
    const int fk   = hi * 8;

    // per-lane transposed mask (VGPR) + uniform empty-row bitmap (SGPR)
    const ull mT = maskT[lane];
    const ull rz = rowzero_p[0];
    // a vectors from global (512B, L2-hot)
    const float4 a1v = *(const float4*)&a[16 * w + 4 * hi];
    const float4 a2v = *(const float4*)&a[64 + 16 * w + 4 * hi];

    // ---- stage X (fp32 -> bf16), coalesced float4, b128 LDS writes ----
    {
        const int c = tid >> 2, q = tid & 3;
        const float* xp = x + (size_t)n * 2097152 + (size_t)c * 32768 + (size_t)t * 64 + q * 16;
        float4 v0 = ((const float4*)xp)[0];
        float4 v1 = ((const float4*)xp)[1];
        float4 v2 = ((const float4*)xp)[2];
        float4 v3 = ((const float4*)xp)[3];
        union { bf16x8 v; unsigned short s[8]; } u0, u1;
        u0.s[0]=f2bf(v0.x); u0.s[1]=f2bf(v0.y); u0.s[2]=f2bf(v0.z); u0.s[3]=f2bf(v0.w);
        u0.s[4]=f2bf(v1.x); u0.s[5]=f2bf(v1.y); u0.s[6]=f2bf(v1.z); u0.s[7]=f2bf(v1.w);
        u1.s[0]=f2bf(v2.x); u1.s[1]=f2bf(v2.y); u1.s[2]=f2bf(v2.z); u1.s[3]=f2bf(v2.w);
        u1.s[4]=f2bf(v3.x); u1.s[5]=f2bf(v3.y); u1.s[6]=f2bf(v3.z); u1.s[7]=f2bf(v3.w);
        *(bf16x8*)&XbYb[c * 72 + q * 16]     = u0.v;
        *(bf16x8*)&XbYb[c * 72 + q * 16 + 8] = u1.v;
    }
    // ---- stage Wt (prepped bf16): 2 coalesced b128 copies per thread ----
    #pragma unroll
    for (int p = 0; p < 2; ++p) {
        const int r  = (tid >> 3) + 32 * p;
        const int cc = (tid & 7) * 8;
        *(bf16x8*)&WtPb[r * 72 + cc] = *(const bf16x8*)&Wt[r * 64 + cc];
    }
    __syncthreads();

    // ---- mm1: Y = X @ W (B from LDS); epilogue: Yb + f/g partials ----
    {
        f32x4 acc[4] = {{0,0,0,0},{0,0,0,0},{0,0,0,0},{0,0,0,0}};
        #pragma unroll
        for (int kc = 0; kc < 2; ++kc) {
            bf16x8 af = *(const bf16x8*)&XbYb[(16 * w + fr) * 72 + 32 * kc + fk];
            #pragma unroll
            for (int cb = 0; cb < 4; ++cb) {
                bf16x8 bfr = *(const bf16x8*)&WtPb[(16 * cb + fr) * 72 + 32 * kc + fk];
                acc[cb] = __builtin_amdgcn_mfma_f32_16x16x32_bf16(af, bfr, acc[cb], 0, 0, 0);
            }
        }
        #pragma unroll
        for (int cb = 0; cb < 4; ++cb) {
            #pragma unroll
            for (int r = 0; r < 4; ++r)
                XbYb[(16 * w + 4 * hi + r) * 72 + 16 * cb + fr] = f2bf(acc[cb][r]);
            float F = acc[cb][0]*a1v.x + acc[cb][1]*a1v.y + acc[cb][2]*a1v.z + acc[cb][3]*a1v.w;
            float G = acc[cb][0]*a2v.x + acc[cb][1]*a2v.y + acc[cb][2]*a2v.z + acc[cb][3]*a2v.w;
            F += __shfl_xor(F, 16, 64); F += __shfl_xor(F, 32, 64);
            G += __shfl_xor(G, 16, 64); G += __shfl_xor(G, 32, 64);
            if (lane < 16) {
                fpart[w][16 * cb + lane] = F;
                gpart[w][16 * cb + lane] = G;
            }
        }
    }
    __syncthreads();

    // ---- softmax rows 16w..16w+15 (unnormalized); fi via readlane ----
    {
        const float gj = (gpart[0][lane] + gpart[1][lane]) + (gpart[2][lane] + gpart[3][lane]);
        const int myv = 16 * w + fr;
        const float ftot = (fpart[0][myv] + fpart[1][myv]) + (fpart[2][myv] + fpart[3][myv]);
        #pragma unroll
        for (int k = 0; k < 16; ++k) {
            const int i = 16 * w + k;
            const float fi = __int_as_float(
                __builtin_amdgcn_readlane(__float_as_int(ftot), k));
            const float s0 = fi + gj;
            const float e  = fmaxf(s0, ALPHA * s0);
            const bool keep = (mT >> i) & 1ull;
            const bool zrow = (rz >> i) & 1ull;
            const float p = zrow ? 1.0f : (keep ? __expf(e) : 0.0f);
            WtPb[i * 72 + lane] = f2bf(p);
        }
    }
    __syncthreads();

    // ---- mm2: out[c,v] = (sum_j Yb[c,j]*P[v,j]) * rcp(S_v); S via ones-MFMA ----
    {
        f32x4 acc2[4] = {{0,0,0,0},{0,0,0,0},{0,0,0,0},{0,0,0,0}};
        f32x4 accS[4] = {{0,0,0,0},{0,0,0,0},{0,0,0,0},{0,0,0,0}};
        union { bf16x8 v; unsigned short s[8]; } ones;
        #pragma unroll
        for (int j = 0; j < 8; ++j) ones.s[j] = 0x3f80;   // bf16 1.0
        #pragma unroll
        for (int kc = 0; kc < 2; ++kc) {
            bf16x8 af = *(const bf16x8*)&XbYb[(16 * w + fr) * 72 + 32 * kc + fk];
            #pragma unroll
            for (int cb = 0; cb < 4; ++cb) {
                bf16x8 bfr = *(const bf16x8*)&WtPb[(16 * cb + fr) * 72 + 32 * kc + fk];
                acc2[cb] = __builtin_amdgcn_mfma_f32_16x16x32_bf16(af, bfr, acc2[cb], 0, 0, 0);
                accS[cb] = __builtin_amdgcn_mfma_f32_16x16x32_bf16(ones.v, bfr, accS[cb], 0, 0, 0);
            }
        }
        float* op = out + (size_t)n * 2097152 + (size_t)t * 64;
        #pragma unroll
        for (int cb = 0; cb < 4; ++cb) {
            const float rs  = __builtin_amdgcn_rcpf(accS[cb][0]);
            const int   col = 16 * cb + fr;
            #pragma unroll
            for (int r = 0; r < 4; ++r) {
                const int row = 16 * w + 4 * hi + r;
                op[(size_t)row * 32768 + col] = acc2[cb][r] * rs;
            }
        }
    }
}

extern "C" void kernel_launch(void* const* d_in, const int* in_sizes, int n_in,
                              void* d_out, int out_size, void* d_ws, size_t ws_size,
                              hipStream_t stream) {
    const float* x = (const float*)d_in[0];
    const float* A = (const float*)d_in[1];
    const float* W = (const float*)d_in[2];
    const float* a = (const float*)d_in[3];
    float* out = (float*)d_out;
    unsigned short* Wt = (unsigned short*)d_ws;          // 8192 B
    ull* maskT   = (ull*)((char*)d_ws + 8192);           // 512 B
    ull* rowzero = (ull*)((char*)d_ws + 8704);           // 8 B

    prep_kernel<<<2, 256, 0, stream>>>(A, W, Wt, maskT, rowzero);
    gat_kernel<<<16 * 512, 256, 0, stream>>>(x, a, Wt, maskT, rowzero, out);
}